// Round 2
// baseline (165.690 us; speedup 1.0000x reference)
//
#include <hip/hip_runtime.h>
#include <math.h>

#define PH 7
#define PW 7
#define B_ 4
#define C_ 256
#define H_ 50
#define W_ 50
#define R_ 256
#define S_ (H_ * W_)     // 2500
#define NCELL (PH * PW)  // 49

// Single kernel, reads features in the ORIGINAL (B,C,H,W) layout — no
// transpose, no workspace, no tmp round-trip.
//
// One wave per (roi, channel). lane = x-offset inside the roi:
//   row segment f[b,c,y,x1..x2] is contiguous in CHW -> one coalesced
//   wave load per row (w <= 50 lanes active).
// Band boundaries (7 row-bands, 7 col-windows) are wave-uniform ints.
// Phase 1: per lane, cm[p] = max over rows of band p at column x1+lane
//          (7 predicated fmax per row; rows loaded once, 2 in flight).
// Phase 2: stage cm[7][64] in LDS; lanes 0..48 reduce one cell's <=8
//          columns; wave stores 49 contiguous floats.
// Block = 4 waves = 4 consecutive channels -> 784 B contiguous store.
// Grid mapping bx = r*64+cg -> XCD = cg%8 (round-robin): each XCD's
// feature working set = 32 ch x 4 batches x 10 KB = 1.28 MB < 4 MB L2.
__global__ void __launch_bounds__(256, 8)
roi_pool_chw(const float* __restrict__ features, const int* __restrict__ rois,
             float* __restrict__ out) {
    __shared__ float cmax[4][PH * 64];
    const int bx   = blockIdx.x;
    const int r    = bx >> 6;          // 0..255
    const int cg   = bx & 63;          // 0..63
    const int wid  = threadIdx.x >> 6; // 0..3
    const int lane = threadIdx.x & 63;
    const int c    = (cg << 2) | wid;  // 0..255

    const int* roi = rois + r * 5;
    const int b  = roi[0];
    const int x1 = roi[1] >> 4;   // floor(v/16), exact for v in [0,800)
    const int y1 = roi[2] >> 4;
    const int x2 = roi[3] >> 4;
    const int y2 = roi[4] >> 4;
    const int h = y2 - y1 + 1;    // 1..50, window always in-bounds
    const int w = x2 - x1 + 1;    // 1..50

    // wave-uniform band boundaries (compiler keeps in SGPRs)
    int shp[PH], ehp[PH];
    #pragma unroll
    for (int p = 0; p < PH; ++p) {
        shp[p] = y1 + (p * h) / PH;
        ehp[p] = y1 + ((p + 1) * h + PH - 1) / PH;   // ceil
    }

    const float* plane = features + ((size_t)b * C_ + c) * S_ + x1 + lane;
    const bool xv = lane < w;

    float cm[PH];
    #pragma unroll
    for (int p = 0; p < PH; ++p) cm[p] = -INFINITY;

    // 2 rows per iteration -> 2 independent loads in flight.
    for (int y = y1; y <= y2; y += 2) {
        const int yb = (y + 1 <= y2) ? (y + 1) : y;      // dup row, max-safe
        const float v0 = xv ? plane[y  * W_] : -INFINITY;
        const float v1 = xv ? plane[yb * W_] : -INFINITY;
        #pragma unroll
        for (int p = 0; p < PH; ++p) {
            // y-range tests are wave-uniform -> scalar-predicated fmax
            if (y  >= shp[p] && y  < ehp[p]) cm[p] = fmaxf(cm[p], v0);
            if (yb >= shp[p] && yb < ehp[p]) cm[p] = fmaxf(cm[p], v1);
        }
    }

    #pragma unroll
    for (int p = 0; p < PH; ++p) cmax[wid][p * 64 + lane] = cm[p];
    __syncthreads();

    if (lane < NCELL) {
        const int p = lane / PW;           // 0..6
        const int q = lane - p * PW;       // 0..6
        const int swr = (q * w) / PW;                  // rel col window
        const int ewr = ((q + 1) * w + PW - 1) / PW;   // <= swr + 8
        float m = -INFINITY;
        for (int k = swr; k < ewr; ++k) m = fmaxf(m, cmax[wid][p * 64 + k]);
        out[((size_t)r * C_ + c) * NCELL + lane] = m;  // 49 contig floats/wave
    }
}

extern "C" void kernel_launch(void* const* d_in, const int* in_sizes, int n_in,
                              void* d_out, int out_size, void* d_ws, size_t ws_size,
                              hipStream_t stream) {
    const float* features = (const float*)d_in[0];
    const int*   rois     = (const int*)d_in[1];
    float*       out      = (float*)d_out;
    (void)d_ws; (void)ws_size;

    roi_pool_chw<<<R_ * 64, 256, 0, stream>>>(features, rois, out);
}

// Round 3
// 90.120 us; speedup vs baseline: 1.8385x; 1.8385x over previous
//
#include <hip/hip_runtime.h>
#include <math.h>

#define PH 7
#define PW 7
#define B_ 4
#define C_ 256
#define H_ 50
#define W_ 50
#define R_ 256
#define S_ (H_ * W_)     // 2500
#define NCELL (PH * PW)  // 49
#define MAXW 9           // max window width: ceil(50/7)+1

// ---------- kernel 1: features (B,C,H,W) -> (B,H,W,C) ----------
__global__ void transpose_chw_hwc(const float* __restrict__ in, float* __restrict__ out) {
    __shared__ float tile[32][33];
    const int b  = blockIdx.z;
    const int s0 = blockIdx.x * 32;
    const int c0 = blockIdx.y * 32;
    const float* inb  = in  + (size_t)b * C_ * S_;
    float*       outb = out + (size_t)b * S_ * C_;
    const int tx = threadIdx.x;
    #pragma unroll
    for (int i = threadIdx.y; i < 32; i += 8) {
        const int s = s0 + tx;
        if (s < S_) tile[i][tx] = inb[(size_t)(c0 + i) * S_ + s];
    }
    __syncthreads();
    #pragma unroll
    for (int i = threadIdx.y; i < 32; i += 8) {
        const int s = s0 + i;
        if (s < S_) outb[(size_t)s * C_ + (c0 + tx)] = tile[tx][i];
    }
}

__device__ __forceinline__ float4 max4(float4 a, float4 b) {
    a.x = fmaxf(a.x, b.x); a.y = fmaxf(a.y, b.y);
    a.z = fmaxf(a.z, b.z); a.w = fmaxf(a.w, b.w);
    return a;
}

// ---------- kernel 2: pool. One wave per (cell, roi). ----------
// Round-0 structure (measured good: 1 KB coalesced load per point, 16
// waves/CU), with the dup-row waste removed: odd-height bands process the
// first row single (was: duplicate full-row reload, ~1.4x extra LLC volume).
__global__ void __launch_bounds__(64, 4)
roi_pool_cell(const float* __restrict__ ft, const int* __restrict__ rois,
              float* __restrict__ tmp) {
    const int bx   = blockIdx.x;
    const int cell = bx >> 8;        // 0..48
    const int r    = bx & 255;       // 0..255
    const int lane = threadIdx.x;    // 0..63

    const int* roi = rois + r * 5;
    const int b  = roi[0];
    const int x1 = roi[1] >> 4;   // floor(v/16), v >= 0
    const int y1 = roi[2] >> 4;
    const int x2 = roi[3] >> 4;
    const int y2 = roi[4] >> 4;
    const int h = y2 - y1 + 1;
    const int w = x2 - x1 + 1;

    const int ph = cell / PW;
    const int pw = cell - ph * PW;
    const int sh = y1 + (ph * h) / PH;
    const int eh = y1 + ((ph + 1) * h + PH - 1) / PH;
    const int sw = x1 + (pw * w) / PW;
    const int ew = x1 + ((pw + 1) * w + PW - 1) / PW;
    const int kw = ew - sw;          // 1..9, wave-uniform

    const float* fb = ft + (size_t)b * S_ * C_ + 4 * lane;

    float4 acc = make_float4(-INFINITY, -INFINITY, -INFINITY, -INFINITY);

    int y = sh;
    if ((eh - sh) & 1) {             // odd band height: single-row prologue
        const float* p0 = fb + (size_t)(y * W_ + sw) * C_;
        float4 v0[MAXW];
        #pragma unroll
        for (int k = 0; k < MAXW; ++k)
            if (k < kw) v0[k] = *(const float4*)(p0 + (size_t)k * C_);
        #pragma unroll
        for (int k = 0; k < MAXW; ++k)
            if (k < kw) acc = max4(acc, v0[k]);
        ++y;
    }
    for (; y < eh; y += 2) {         // even remainder: true row pairs
        const float* p0 = fb + (size_t)( y      * W_ + sw) * C_;
        const float* p1 = fb + (size_t)((y + 1) * W_ + sw) * C_;
        float4 v0[MAXW], v1[MAXW];
        #pragma unroll
        for (int k = 0; k < MAXW; ++k) {
            if (k < kw) {                            // wave-uniform branch
                v0[k] = *(const float4*)(p0 + (size_t)k * C_);
                v1[k] = *(const float4*)(p1 + (size_t)k * C_);
            }
        }
        #pragma unroll
        for (int k = 0; k < MAXW; ++k) {
            if (k < kw) acc = max4(acc, max4(v0[k], v1[k]));
        }
    }

    *(float4*)(tmp + ((size_t)(r * NCELL + cell)) * C_ + 4 * lane) = acc;
}

// ---------- kernel 3: tmp (R,49,C) -> out (R,C,49) ----------
// Split each roi across 2 blocks (128-channel halves): 512 blocks instead of
// 256 (2 blocks/CU), 25 KB LDS instead of 50. Stride 129 (129%32==1):
// conflict-free on both LDS phases; both global phases fully coalesced.
__global__ void __launch_bounds__(256)
transpose_out(const float* __restrict__ tmp, float* __restrict__ out) {
    __shared__ float lds[NCELL * 129];  // 25.3 KB
    const int r    = blockIdx.x >> 1;
    const int c0   = (blockIdx.x & 1) << 7;   // 0 or 128
    const int t    = threadIdx.x;
    const float* src = tmp + (size_t)r * NCELL * C_ + c0;
    float*       dst = out + (size_t)r * C_ * NCELL + (size_t)c0 * NCELL;

    #pragma unroll
    for (int i = t; i < NCELL * 128; i += 256) {
        const int cell = i >> 7;         // i = cell*128 + c
        const int c    = i & 127;
        lds[cell * 129 + c] = src[(size_t)cell * C_ + c];
    }
    __syncthreads();
    #pragma unroll
    for (int f = t; f < 128 * NCELL; f += 256) {
        const int c    = f / NCELL;      // const divisor -> magic mul
        const int cell = f - c * NCELL;  // f = c*49 + cell
        dst[f] = lds[cell * 129 + c];
    }
}

extern "C" void kernel_launch(void* const* d_in, const int* in_sizes, int n_in,
                              void* d_out, int out_size, void* d_ws, size_t ws_size,
                              hipStream_t stream) {
    const float* features = (const float*)d_in[0];
    const int*   rois     = (const int*)d_in[1];
    float*       out      = (float*)d_out;

    float* ft  = (float*)d_ws;                       // 10.24 MB
    float* tmp = ft + (size_t)B_ * S_ * C_;          // +12.85 MB (ws is 256 MB)

    dim3 tgrid((S_ + 31) / 32, C_ / 32, B_);
    transpose_chw_hwc<<<tgrid, dim3(32, 8), 0, stream>>>(features, ft);
    roi_pool_cell<<<NCELL * R_, 64, 0, stream>>>(ft, rois, tmp);
    transpose_out<<<R_ * 2, 256, 0, stream>>>(tmp, out);
}